// Round 10
// baseline (1053.837 us; speedup 1.0000x reference)
//
#include <hip/hip_runtime.h>
#include <hip/hip_bf16.h>
#include <math.h>

#define NN 30000
#define NE 480000
#define NLAYER 4
#define NGR 32
#define NOUT 12
#define EPS_BN 1e-5f
#define EPS_STD 1e-5f
#define AVG_LOG 1.3821454785305053f
#define MB_GRID 235   // (NN+127)/128
#define MB2 469       // (NN+63)/64

typedef unsigned short ushort_t;
typedef __bf16 bf16x8 __attribute__((ext_vector_type(8)));
typedef float floatx4 __attribute__((ext_vector_type(4)));

__device__ __forceinline__ float bfu(ushort_t u){
  union { unsigned int ui; float f; } c; c.ui = ((unsigned int)u) << 16; return c.f;
}
__device__ __forceinline__ ushort_t f2bf(float f){
  union { float f; unsigned int u; } c; c.f = f;
  unsigned int lsb = (c.u >> 16) & 1u;
  c.u += 0x7FFFu + lsb;
  return (ushort_t)(c.u >> 16);
}

// ---------------- runtime dtype detection ----------------
__device__ __forceinline__ int plausible(unsigned int bits32){
  unsigned int e = (bits32 >> 23) & 0xFF;
  if(e == 0xFF) return 0;
  if(bits32 == 0 || bits32 == 0x80000000u) return 1;
  return (e >= 93 && e <= 140) ? 1 : 0;
}

__global__ void k_detect(const ushort_t* __restrict__ xr, int* __restrict__ flag){
  __shared__ int cnt[2];
  if(threadIdx.x < 2) cnt[threadIdx.x] = 0;
  __syncthreads();
  const unsigned int* xf = (const unsigned int*)xr;
  int gf = 0, gb = 0;
  for(int i = threadIdx.x; i < 1024; i += 256){
    gf += plausible(xf[i]);
    gb += plausible(((unsigned int)xr[i]) << 16);
  }
  atomicAdd(&cnt[0], gf);
  atomicAdd(&cnt[1], gb);
  __syncthreads();
  if(threadIdx.x == 0) *flag = (cnt[1] >= cnt[0]) ? 1 : 0;
}

// ---------------- batched conversion to fp32 ----------------
#define NJOBS 18
struct CvtJob { const void* s; float* d; int n; };
struct CvtArgs { CvtJob j[NJOBS]; const int* flag; };

__global__ void k_cvt(CvtArgs a){
  int ji = blockIdx.y;
  const int isbf = *a.flag;
  float* d = a.j[ji].d;
  int n = a.j[ji].n;
  if(isbf){
    const ushort_t* s = (const ushort_t*)a.j[ji].s;
    for(int i = blockIdx.x*256 + threadIdx.x; i < n; i += gridDim.x*256) d[i] = bfu(s[i]);
  } else {
    const float* s = (const float*)a.j[ji].s;
    for(int i = blockIdx.x*256 + threadIdx.x; i < n; i += gridDim.x*256) d[i] = s[i];
  }
}

__global__ void k_xbf(const void* __restrict__ x, ushort_t* __restrict__ d,
                      const int* __restrict__ flag){
  int i = blockIdx.x*256 + threadIdx.x;
  if(i >= NN*64) return;
  if(*flag) d[i] = ((const ushort_t*)x)[i];
  else      d[i] = f2bf(((const float*)x)[i]);
}

// ---------------- tiled transpose fp32[K,N] -> bf16[N,K] ----------------
#define NTR 9
struct TrJob { const float* s; ushort_t* d; int K, N; };
struct TrArgs { TrJob j[NTR]; };

__global__ void k_tr(TrArgs a){
  TrJob j = a.j[blockIdx.y];
  int nk = j.K >> 6, nn = j.N >> 6;
  int tile = blockIdx.x;
  if(tile >= nk*nn) return;
  int tk = tile % nk, tn = tile / nk;
  int k0 = tk*64, n0 = tn*64;
  __shared__ float t[64][65];
  int w = threadIdx.x >> 6, c = threadIdx.x & 63;
  #pragma unroll
  for(int i=0;i<16;i+=1){
    int r = i*4 + w;
    t[r][c] = j.s[(size_t)(k0+r)*j.N + n0 + c];
  }
  __syncthreads();
  #pragma unroll
  for(int i=0;i<16;i+=1){
    int r = i*4 + w;
    j.d[(size_t)(n0+r)*j.K + k0 + c] = f2bf(t[c][r]);
  }
}

// ---------------- fold: D[n,k] = sum_t S1[k,t]*S2[t,n]  (bf16 out) ----------------
#define NFOLD 16
struct FoldJob { const float* s1; const float* s2; ushort_t* d; int Kd; };
struct FoldArgs { FoldJob j[NFOLD]; };

__global__ void k_fold(FoldArgs a){
  FoldJob j = a.j[blockIdx.y];
  const int n0 = blockIdx.x*16;
  __shared__ float s2s[128][16];
  int tid = threadIdx.x;
  for(int idx = tid; idx < 128*16; idx += 256){
    int t = idx >> 4, jj = idx & 15;
    s2s[t][jj] = j.s2[t*128 + n0 + jj];
  }
  __syncthreads();
  for(int k = tid; k < j.Kd; k += 256){
    float part[16];
    #pragma unroll
    for(int p=0;p<16;p++) part[p] = 0.f;
    for(int t0=0; t0<128; t0+=32){
      float rr[32];
      #pragma unroll
      for(int tt=0;tt<32;tt++) rr[tt] = j.s1[(size_t)k*128 + t0 + tt];
      #pragma unroll
      for(int p=0;p<16;p++){
        float acc = 0.f;
        #pragma unroll
        for(int tt=0;tt<32;tt++) acc += rr[tt]*s2s[t0+tt][p];
        part[p] += acc;
      }
    }
    #pragma unroll
    for(int p=0;p<16;p++)
      j.d[(size_t)(n0+p)*j.Kd + k] = f2bf(part[p]);
  }
}

__global__ void k_foldb(const float* __restrict__ postB, const float* __restrict__ linW,
                        const float* __restrict__ linB, float* __restrict__ biasY){
  int l = blockIdx.x, c = threadIdx.x;
  float a = linB[l*128+c];
  const float* L = linW + (size_t)l*128*128;
  const float* pb = postB + l*128;
  for(int t=0;t<128;t++) a += pb[t]*L[t*128+c];
  biasY[l*128+c] = a;
}

// ---------------- CSR build ----------------
__global__ void k_deg(const int* __restrict__ dst, int* __restrict__ deg){
  int i = blockIdx.x*256 + threadIdx.x;
  if(i < NE){
    unsigned d = (unsigned)dst[i];
    if(d < NN) atomicAdd(&deg[d], 1);
  }
}

__global__ void k_scan1(const int* __restrict__ deg, int* __restrict__ rp,
                        int* __restrict__ bsum){
  __shared__ int wsum[16];
  int tid = threadIdx.x, lane = tid & 63, wid = tid >> 6;
  int i = blockIdx.x*1024 + tid;
  int v = (i < NN) ? deg[i] : 0;
  int incl = v;
  #pragma unroll
  for(int off=1; off<64; off<<=1){
    int t = __shfl_up(incl, off, 64);
    if(lane >= off) incl += t;
  }
  if(lane==63) wsum[wid] = incl;
  __syncthreads();
  int woff = 0;
  for(int w=0; w<wid; w++) woff += wsum[w];
  if(i < NN) rp[i+1] = incl + woff;
  if(tid == 0){
    int t = 0;
    for(int w=0; w<16; w++) t += wsum[w];
    bsum[blockIdx.x] = t;
  }
}

__global__ void k_scan2(const int* __restrict__ bsum, int* __restrict__ boff,
                        int* __restrict__ rp, int nb){
  if(threadIdx.x == 0){
    int run = 0;
    for(int b=0;b<nb;b++){ boff[b] = run; run += bsum[b]; }
    rp[0] = 0;
  }
}

__global__ void k_scan3(int* __restrict__ rp, const int* __restrict__ boff){
  int i = blockIdx.x*1024 + threadIdx.x;
  if(i < NN) rp[i+1] += boff[blockIdx.x];
}

__global__ void k_scatter(const int* __restrict__ dst,
                          const int* __restrict__ rp, int* __restrict__ fill,
                          int* __restrict__ eix_csr){
  int i = blockIdx.x*256 + threadIdx.x;
  if(i >= NE) return;
  unsigned d = (unsigned)dst[i];
  if(d >= NN) return;
  int pos = rp[d] + atomicAdd(&fill[d], 1);
  eix_csr[pos] = i;
}

// canonical per-node order: LDS insertion sort of edge ids (keys only)
__launch_bounds__(64)
__global__ void k_srt(const int* __restrict__ rp, int* __restrict__ eix){
  __shared__ int buf[64][129];
  int t = threadIdx.x;
  int n = blockIdx.x*64 + t;
  if(n >= NN) return;
  int s0 = rp[n], e0 = rp[n+1], d = e0 - s0;
  if(d <= 1) return;
  if(d <= 128){
    int* b = buf[t];
    for(int i=0;i<d;i++) b[i] = eix[s0+i];
    for(int i=1;i<d;i++){
      int k = b[i], j = i-1;
      while(j >= 0 && b[j] > k){ b[j+1] = b[j]; j--; }
      b[j+1] = k;
    }
    for(int i=0;i<d;i++) eix[s0+i] = b[i];
  } else {
    for(int i=s0+1;i<e0;i++){
      int k = eix[i], j = i-1;
      while(j >= s0 && eix[j] > k){ eix[j+1] = eix[j]; j--; }
      eix[j+1] = k;
    }
  }
}

// gather edge_attr (bf16) + src ids into CSR order
__global__ void k_gather_ea(const int* __restrict__ eix, const int* __restrict__ esrc,
                            const void* __restrict__ ea,
                            ushort_t* __restrict__ out, int* __restrict__ src_csr,
                            const int* __restrict__ flag){
  int j = blockIdx.x*128 + threadIdx.x;
  if(j >= NE) return;
  int i = eix[j];
  src_csr[j] = esrc[i];
  uint4* d = (uint4*)(out + (size_t)j*16);
  if(*flag){
    const uint4* s = (const uint4*)((const ushort_t*)ea + (size_t)i*16);
    d[0] = s[0]; d[1] = s[1];
  } else {
    const float* s = (const float*)ea + (size_t)i*16;
    union { ushort_t us[16]; uint4 u4[2]; } pk;
    #pragma unroll
    for(int k=0;k<16;k++) pk.us[k] = f2bf(s[k]);
    d[0] = pk.u4[0]; d[1] = pk.u4[1];
  }
}

// ---------------- Kf prep ----------------
__global__ void k_prep_K(const float* __restrict__ embW, const float* __restrict__ embB,
                         const float* __restrict__ encW, const float* __restrict__ encB,
                         const float* __restrict__ preW, const float* __restrict__ preB,
                         float* __restrict__ Kf){
  int bx = blockIdx.x;
  int l = bx / 17, r = bx % 17;
  int c = threadIdx.x;
  const float* eW = encW + (size_t)l*128*128;
  const float* P3 = preW + (size_t)l*384*128 + 256*128;
  __shared__ float trow[128];
  float a;
  if(r < 16){
    a = 0.f;
    const float* w = embW + r*128;
    for(int k=0;k<128;k++) a += w[k]*eW[k*128+c];
  } else {
    a = encB[l*128+c];
    for(int k=0;k<128;k++) a += embB[k]*eW[k*128+c];
  }
  trow[c] = a;
  __syncthreads();
  float o = (r==16) ? preB[l*128+c] : 0.f;
  for(int k=0;k<128;k++) o += trow[k]*P3[k*128+c];
  Kf[(size_t)l*17*128 + r*128 + c] = o;
}

// Kf -> MFMA B-fragment order: KfT[l][t][lane][j] = (k=quad*8+j) < 16 ? Kf[l][k][t*16+l15] : 0
// plus fp32 bias row copy.
__global__ void k_prep_Kfrag(const float* __restrict__ Kf, ushort_t* __restrict__ KfT,
                             float* __restrict__ Kfb){
  int b = blockIdx.x;            // l*8 + t
  int l = b >> 3, t = b & 7;
  int lane = threadIdx.x;        // 64
  int quad = lane >> 4, l15 = lane & 15;
  const float* K = Kf + (size_t)l*17*128;
  ushort_t* o = KfT + (((size_t)l*8 + t)*64 + lane)*8;
  #pragma unroll
  for(int j=0;j<8;j++){
    int k = quad*8 + j;
    int col = t*16 + l15;
    o[j] = (k < 16) ? f2bf(K[k*128 + col]) : (ushort_t)0;
  }
  if(t == 0){
    Kfb[l*128 + lane]      = K[16*128 + lane];
    Kfb[l*128 + lane + 64] = K[16*128 + lane + 64];
  }
}

// ---------------- bf16 MFMA GEMM: C[M,N] = A[M,K] @ BT[N,K]^T ----------------
// EPI 0: +bias(optional), OUTBF store type.
// EPI 2: mixed AB output: col-block 0 -> fp32 C (Ah), col-block 1 -> bf16 C2 (Bh).
template<int EPI, int OUTBF>
__launch_bounds__(256)
__global__ void k_mm(const ushort_t* __restrict__ A, const ushort_t* __restrict__ BT,
                     void* __restrict__ C, void* __restrict__ C2,
                     int M, int K, int ldc, const float* __restrict__ bias){
  __shared__ __align__(16) ushort_t Als[128][88];
  __shared__ __align__(16) ushort_t Bls[128][88];
  const int tid = threadIdx.x;
  const int m0 = blockIdx.x*128, n0 = blockIdx.y*128;
  const int w = tid >> 6, lane = tid & 63;
  const int wm = (w & 1)*64, wn = (w >> 1)*64;
  const int quad = lane >> 4, l15 = lane & 15;
  floatx4 acc[4][4] = {};

  for(int k0=0; k0<K; k0+=64){
    #pragma unroll
    for(int i=0;i<4;i++){
      int c = tid + 256*i;
      int row = c >> 3, kc = (c & 7)*8;
      uint4 va = make_uint4(0u,0u,0u,0u);
      int gr = m0 + row;
      if(gr < M) va = *(const uint4*)(A + (size_t)gr*K + k0 + kc);
      *(uint4*)(&Als[row][kc]) = va;
      uint4 vb = *(const uint4*)(BT + (size_t)(n0+row)*K + k0 + kc);
      *(uint4*)(&Bls[row][kc]) = vb;
    }
    __syncthreads();
    #pragma unroll
    for(int ks=0; ks<64; ks+=32){
      bf16x8 a[4], b[4];
      #pragma unroll
      for(int i=0;i<4;i++) a[i] = *(const bf16x8*)(&Als[wm+16*i+l15][ks+quad*8]);
      #pragma unroll
      for(int j=0;j<4;j++) b[j] = *(const bf16x8*)(&Bls[wn+16*j+l15][ks+quad*8]);
      #pragma unroll
      for(int i=0;i<4;i++)
        #pragma unroll
        for(int j=0;j<4;j++)
          acc[i][j] = __builtin_amdgcn_mfma_f32_16x16x32_bf16(a[i], b[j], acc[i][j], 0, 0, 0);
    }
    __syncthreads();
  }

  #pragma unroll
  for(int i=0;i<4;i++){
    #pragma unroll
    for(int r=0;r<4;r++){
      int grow = m0 + wm + 16*i + quad*4 + r;
      if(grow >= M) continue;
      #pragma unroll
      for(int j=0;j<4;j++){
        int gcol = n0 + wn + 16*j + l15;
        float v = acc[i][j][r];
        if(EPI==0){
          if(bias) v += bias[gcol];
          if(OUTBF) ((ushort_t*)C)[(size_t)grow*ldc + gcol] = f2bf(v);
          else      ((float*)  C)[(size_t)grow*ldc + gcol] = v;
        } else {  // EPI==2 mixed
          if(n0 == 0) ((float*)C)[(size_t)grow*128 + gcol] = v;
          else        ((ushort_t*)C2)[(size_t)grow*128 + (gcol-128)] = f2bf(v);
        }
      }
    }
  }
}

// ---------------- fused post GEMM, 64-row tiles ----------------
// y = agg@Wcat (3 amp-combined panels) + h@W0f + biasY ; bf16 y + BN partials.
__launch_bounds__(256)
__global__ void k_post(const ushort_t* __restrict__ aggb, const ushort_t* __restrict__ h,
                       const ushort_t* __restrict__ Wcat, const ushort_t* __restrict__ W0,
                       const float* __restrict__ biasY,
                       const float* __restrict__ ampv, const float* __restrict__ invv,
                       ushort_t* __restrict__ y, float* __restrict__ bnpart){
  __shared__ __align__(16) ushort_t Als[64][88];
  __shared__ __align__(16) ushort_t Bls[128][88];
  __shared__ float s_part[4][128];
  __shared__ float q_part[4][128];
  __shared__ float amp_s[64];
  __shared__ float inv_s[64];
  const int tid = threadIdx.x;
  const int m0 = blockIdx.x*64;
  const int w = tid >> 6, lane = tid & 63;
  const int quad = lane >> 4, l15 = lane & 15;
  const int cw = w*32;
  if(tid < 64){
    int rr = min(m0 + tid, NN-1);
    amp_s[tid] = ampv[rr];
    inv_s[tid] = invv[rr];
  }
  floatx4 accY[4][2] = {};

  for(int p=0; p<3; p++){
    floatx4 accP[4][2] = {};
    floatx4 (*tgt)[2] = (p==0) ? accY : accP;
    const ushort_t* Wp = Wcat + (size_t)p*128*512;
    for(int k0=0; k0<512; k0+=64){
      #pragma unroll
      for(int i=0;i<2;i++){
        int c = tid + 256*i;
        int row = c >> 3, kc = (c & 7)*8;
        uint4 va = make_uint4(0u,0u,0u,0u);
        int gr = m0 + row;
        if(gr < NN) va = *(const uint4*)(aggb + (size_t)gr*512 + k0 + kc);
        *(uint4*)(&Als[row][kc]) = va;
      }
      #pragma unroll
      for(int i=0;i<4;i++){
        int c = tid + 256*i;
        int row = c >> 3, kc = (c & 7)*8;
        *(uint4*)(&Bls[row][kc]) = *(const uint4*)(Wp + (size_t)row*512 + k0 + kc);
      }
      __syncthreads();
      #pragma unroll
      for(int ks=0; ks<64; ks+=32){
        bf16x8 a[4], b[2];
        #pragma unroll
        for(int i=0;i<4;i++) a[i] = *(const bf16x8*)(&Als[16*i+l15][ks+quad*8]);
        #pragma unroll
        for(int j=0;j<2;j++) b[j] = *(const bf16x8*)(&Bls[cw+16*j+l15][ks+quad*8]);
        #pragma unroll
        for(int i=0;i<4;i++)
          #pragma unroll
          for(int j=0;j<2;j++)
            tgt[i][j] = __builtin_amdgcn_mfma_f32_16x16x32_bf16(a[i], b[j], tgt[i][j], 0, 0, 0);
      }
      __syncthreads();
    }
    if(p > 0){
      const float* cs = (p==1) ? amp_s : inv_s;
      #pragma unroll
      for(int i=0;i<4;i++)
        #pragma unroll
        for(int r=0;r<4;r++){
          float coef = cs[16*i + quad*4 + r];
          #pragma unroll
          for(int j=0;j<2;j++) accY[i][j][r] += coef*accP[i][j][r];
        }
    }
  }

  // + h @ W0f  (K=128)
  for(int k0=0; k0<128; k0+=64){
    #pragma unroll
    for(int i=0;i<2;i++){
      int c = tid + 256*i;
      int row = c >> 3, kc = (c & 7)*8;
      uint4 va = make_uint4(0u,0u,0u,0u);
      int gr = m0 + row;
      if(gr < NN) va = *(const uint4*)(h + (size_t)gr*128 + k0 + kc);
      *(uint4*)(&Als[row][kc]) = va;
    }
    #pragma unroll
    for(int i=0;i<4;i++){
      int c = tid + 256*i;
      int row = c >> 3, kc = (c & 7)*8;
      *(uint4*)(&Bls[row][kc]) = *(const uint4*)(W0 + (size_t)row*128 + k0 + kc);
    }
    __syncthreads();
    #pragma unroll
    for(int ks=0; ks<64; ks+=32){
      bf16x8 a[4], b[2];
      #pragma unroll
      for(int i=0;i<4;i++) a[i] = *(const bf16x8*)(&Als[16*i+l15][ks+quad*8]);
      #pragma unroll
      for(int j=0;j<2;j++) b[j] = *(const bf16x8*)(&Bls[cw+16*j+l15][ks+quad*8]);
      #pragma unroll
      for(int i=0;i<4;i++)
        #pragma unroll
        for(int j=0;j<2;j++)
          accY[i][j] = __builtin_amdgcn_mfma_f32_16x16x32_bf16(a[i], b[j], accY[i][j], 0, 0, 0);
    }
    __syncthreads();
  }

  float s[2] = {0,0}, q[2] = {0,0};
  #pragma unroll
  for(int i=0;i<4;i++){
    #pragma unroll
    for(int r=0;r<4;r++){
      int grow = m0 + 16*i + quad*4 + r;
      if(grow >= NN) continue;
      #pragma unroll
      for(int j=0;j<2;j++){
        int gcol = cw + 16*j + l15;
        float v = accY[i][j][r] + biasY[gcol];
        y[(size_t)grow*128 + gcol] = f2bf(v);
        s[j] += v; q[j] += v*v;
      }
    }
  }
  #pragma unroll
  for(int j=0;j<2;j++){
    s_part[quad][cw + 16*j + l15] = s[j];
    q_part[quad][cw + 16*j + l15] = q[j];
  }
  __syncthreads();
  if(tid < 128){
    float ss = 0.f, qq = 0.f;
    #pragma unroll
    for(int sl=0; sl<4; sl++){ ss += s_part[sl][tid]; qq += q_part[sl][tid]; }
    bnpart[(size_t)blockIdx.x*256 + tid]       = ss;
    bnpart[(size_t)blockIdx.x*256 + 128 + tid] = qq;
  }
}

// ---------------- PNA aggregation: MFMA em + C-layout aggregation ----------------
__launch_bounds__(128)
__global__ void k_agg(const int* __restrict__ rp, const int* __restrict__ src_csr,
                      const ushort_t* __restrict__ ea_csr,
                      const ushort_t* __restrict__ KfT, const float* __restrict__ Kfb,
                      const float* __restrict__ Ah, const ushort_t* __restrict__ Bh,
                      ushort_t* __restrict__ agg, float* __restrict__ ampv,
                      float* __restrict__ invv){
  const int n = blockIdx.x, tid = threadIdx.x;
  const int wv = tid >> 6, lane = tid & 63;
  const int quad = lane >> 4, l15 = lane & 15;
  const int s0 = rp[n], e0 = rp[n+1], deg = e0 - s0;
  bf16x8 kf[4];
  float base[4];
  #pragma unroll
  for(int tt=0;tt<4;tt++){
    int t = wv*4 + tt;
    kf[tt] = *(const bf16x8*)(KfT + ((size_t)t*64 + lane)*8);
    int col = wv*64 + tt*16 + l15;
    base[tt] = Ah[(size_t)n*128 + col] + Kfb[col];
  }
  float sum[4], sq[4], mn[4], mx[4];
  #pragma unroll
  for(int tt=0;tt<4;tt++){ sum[tt]=0.f; sq[tt]=0.f; mn[tt]=INFINITY; mx[tt]=-INFINITY; }
  __shared__ __align__(16) ushort_t ea_s[16][16];
  __shared__ int src_s[16];

  for(int j0=s0; j0<e0; j0+=16){
    int cnt = min(16, e0-j0);
    __syncthreads();
    {
      int edge = tid >> 3, pos = (tid & 7)*2;
      int se = j0 + min(edge, cnt-1);
      *(unsigned int*)(&ea_s[edge][pos]) = *(const unsigned int*)(ea_csr + (size_t)se*16 + pos);
    }
    if(tid < 16) src_s[tid] = src_csr[min(j0+tid, e0-1)];
    __syncthreads();
    bf16x8 af = {};
    if(quad < 2) af = *(const bf16x8*)(&ea_s[l15][quad*8]);
    #pragma unroll
    for(int tt=0;tt<4;tt++){
      floatx4 zc = {0.f,0.f,0.f,0.f};
      floatx4 em = __builtin_amdgcn_mfma_f32_16x16x32_bf16(af, kf[tt], zc, 0, 0, 0);
      int col = wv*64 + tt*16 + l15;
      #pragma unroll
      for(int r=0;r<4;r++){
        int e = quad*4 + r;
        float bh = bfu(Bh[(size_t)src_s[e]*128 + col]);
        float m = base[tt] + bh + em[r];
        if(e < cnt){
          sum[tt] += m; sq[tt] += m*m;
          mn[tt] = fminf(mn[tt], m); mx[tt] = fmaxf(mx[tt], m);
        }
      }
    }
  }

  // cross-quad reduce (lanes l, l^16, l^32 share a column)
  #pragma unroll
  for(int tt=0;tt<4;tt++){
    sum[tt] += __shfl_xor(sum[tt], 16); sum[tt] += __shfl_xor(sum[tt], 32);
    sq[tt]  += __shfl_xor(sq[tt], 16);  sq[tt]  += __shfl_xor(sq[tt], 32);
    mn[tt] = fminf(mn[tt], __shfl_xor(mn[tt], 16)); mn[tt] = fminf(mn[tt], __shfl_xor(mn[tt], 32));
    mx[tt] = fmaxf(mx[tt], __shfl_xor(mx[tt], 16)); mx[tt] = fmaxf(mx[tt], __shfl_xor(mx[tt], 32));
  }
  if(quad == 0){
    float degc = (float)(deg>0?deg:1);
    ushort_t* o = agg + (size_t)n*512;
    #pragma unroll
    for(int tt=0;tt<4;tt++){
      int col = wv*64 + tt*16 + l15;
      float mean = sum[tt]/degc;
      float var = fmaxf(sq[tt]/degc - mean*mean, 0.f);
      float sd = sqrtf(var + EPS_STD);
      float lmn = (deg==0) ? 0.f : mn[tt];
      float lmx = (deg==0) ? 0.f : mx[tt];
      o[col]       = f2bf(mean);
      o[128 + col] = f2bf(lmn);
      o[256 + col] = f2bf(lmx);
      o[384 + col] = f2bf(sd);
    }
  }
  if(tid == 0){
    float degc = (float)(deg>0?deg:1);
    float amp = logf(degc+1.f)/AVG_LOG;
    ampv[n] = amp; invv[n] = 1.f/amp;
  }
}

// ---------------- batchnorm ----------------
__global__ void k_bn_fin(const float* __restrict__ bnpart, int nb,
                         const float* __restrict__ gamma, const float* __restrict__ beta,
                         float* __restrict__ scale, float* __restrict__ shift){
  int c = threadIdx.x;
  float s0=0.f,s1=0.f,s2=0.f,s3=0.f, q0=0.f,q1=0.f,q2=0.f,q3=0.f;
  int b = 0;
  for(; b+3<nb; b+=4){
    s0 += bnpart[(size_t)(b+0)*256 + c];       q0 += bnpart[(size_t)(b+0)*256 + 128 + c];
    s1 += bnpart[(size_t)(b+1)*256 + c];       q1 += bnpart[(size_t)(b+1)*256 + 128 + c];
    s2 += bnpart[(size_t)(b+2)*256 + c];       q2 += bnpart[(size_t)(b+2)*256 + 128 + c];
    s3 += bnpart[(size_t)(b+3)*256 + c];       q3 += bnpart[(size_t)(b+3)*256 + 128 + c];
  }
  for(; b<nb; b++){ s0 += bnpart[(size_t)b*256 + c]; q0 += bnpart[(size_t)b*256 + 128 + c]; }
  float s = (s0+s1)+(s2+s3), q = (q0+q1)+(q2+q3);
  float mu  = s*(1.f/NN);
  float var = fmaxf(q*(1.f/NN) - mu*mu, 0.f);
  float inv = 1.f/sqrtf(var + EPS_BN);
  float sc = gamma[c]*inv;
  scale[c] = sc;
  shift[c] = beta[c] - mu*sc;
}

__global__ void k_bn_relu(const ushort_t* __restrict__ y, const float* __restrict__ scale,
                          const float* __restrict__ shift, ushort_t* __restrict__ h){
  int i = blockIdx.x*256 + threadIdx.x;
  if(i >= NN*128) return;
  int c = i & 127;
  float v = fmaxf(bfu(y[i])*scale[c] + shift[c], 0.f);
  h[i] = f2bf(v);
}

// ---------------- pooling (deterministic, chunked) + head ----------------
__device__ __forceinline__ int lbound(const int* a, int n, int v){
  int lo = 0, hi = n;
  while(lo < hi){ int mid = (lo+hi) >> 1; if(a[mid] < v) lo = mid+1; else hi = mid; }
  return lo;
}

__launch_bounds__(128)
__global__ void k_pool1(const ushort_t* __restrict__ h, const int* __restrict__ batch,
                        float* __restrict__ gpart){
  int b = blockIdx.x, ch = blockIdx.y, c = threadIdx.x;
  int lo = lbound(batch, NN, b), hi = lbound(batch, NN, b+1);
  int len = hi - lo;
  int per = (len + 7) >> 3;
  int r0 = min(lo + ch*per, hi);
  int r1 = min(r0 + per, hi);
  float acc = 0.f;
  for(int r=r0;r<r1;r++) acc += bfu(h[(size_t)r*128+c]);
  gpart[((size_t)b*8 + ch)*128 + c] = acc;
}

__global__ void k_pool2(const float* __restrict__ gpart, float* __restrict__ g){
  int b = blockIdx.x, c = threadIdx.x;
  float acc = 0.f;
  #pragma unroll
  for(int ch=0; ch<8; ch++) acc += gpart[((size_t)b*8 + ch)*128 + c];
  g[(size_t)b*128 + c] = acc;
}

__launch_bounds__(64)
__global__ void k_head(const float* __restrict__ g, const float* __restrict__ W1,
                       const float* __restrict__ b1, const float* __restrict__ W2,
                       const float* __restrict__ b2, void* __restrict__ out,
                       const int* __restrict__ flag){
  __shared__ float gs[128];
  __shared__ float zs[64];
  int r = blockIdx.x, tid = threadIdx.x;
  gs[tid] = g[r*128 + tid];
  gs[tid+64] = g[r*128 + tid + 64];
  __syncthreads();
  float a = b1[tid];
  for(int k=0;k<128;k++) a += gs[k]*W1[k*64+tid];
  zs[tid] = fmaxf(a, 0.f);
  __syncthreads();
  if(tid < NOUT){
    float o = b2[tid];
    for(int k=0;k<64;k++) o += zs[k]*W2[k*12+tid];
    if(*flag) ((ushort_t*)out)[r*NOUT + tid] = f2bf(o);
    else      ((float*)out)[r*NOUT + tid] = o;
  }
}

// ---------------- host ----------------
extern "C" void kernel_launch(void* const* d_in, const int* in_sizes, int n_in,
                              void* d_out, int out_size, void* d_ws, size_t ws_size,
                              hipStream_t stream){
  const void* x_raw = d_in[0];
  const void* ea_raw;
  const int*  eidx;
  const int*  batch;
  if(in_sizes[1] == 2*NE){           // signature order
    eidx   = (const int*)d_in[1];
    batch  = (const int*)d_in[2];
    ea_raw = d_in[3];
  } else {                           // dict order
    ea_raw = d_in[1];
    eidx   = (const int*)d_in[2];
    batch  = (const int*)d_in[3];
  }
  const void* nembW_r = d_in[4];
  const void* nembB_r = d_in[5];
  const void* eembW_r = d_in[6];
  const void* eembB_r = d_in[7];
  const void* encW_r  = d_in[8];
  const void* encB_r  = d_in[9];
  const void* preW_r  = d_in[10];
  const void* preB_r  = d_in[11];
  const void* postW_r = d_in[12];
  const void* postB_r = d_in[13];
  const void* linW_r  = d_in[14];
  const void* linB_r  = d_in[15];
  const void* bnG_r   = d_in[16];
  const void* bnB_r   = d_in[17];
  const void* h1W_r   = d_in[18];
  const void* h1B_r   = d_in[19];
  const void* h2W_r   = d_in[20];
  const void* h2B_r   = d_in[21];

  char* p = (char*)d_ws;
  auto alloc = [&](size_t bytes)->void*{
    void* r = (void*)p; p += (bytes + 255) & ~(size_t)255; return r;
  };
  int*      dtflag  = (int*)     alloc(sizeof(int)*16);
  int*      deg     = (int*)     alloc(sizeof(int)*NN);
  int*      fill    = (int*)     alloc(sizeof(int)*NN);
  int*      rp      = (int*)     alloc(sizeof(int)*(NN+1));
  int*      bsum    = (int*)     alloc(sizeof(int)*64);
  int*      boff    = (int*)     alloc(sizeof(int)*64);
  int*      src_csr = (int*)     alloc(sizeof(int)*NE);
  int*      eix_csr = (int*)     alloc(sizeof(int)*NE);
  ushort_t* ea_csr  = (ushort_t*)alloc(sizeof(ushort_t)*(size_t)NE*16);
  ushort_t* xbf     = (ushort_t*)alloc(sizeof(ushort_t)*(size_t)NN*64);
  ushort_t* h       = (ushort_t*)alloc(sizeof(ushort_t)*(size_t)NN*128);
  ushort_t* aggb    = (ushort_t*)alloc(sizeof(ushort_t)*(size_t)NN*512);
  float*    Ah      = (float*)   alloc(sizeof(float)*(size_t)NN*128);
  ushort_t* Bh      = (ushort_t*)alloc(sizeof(ushort_t)*(size_t)NN*128);
  ushort_t* y       = (ushort_t*)alloc(sizeof(ushort_t)*(size_t)NN*128);
  float*    ampv    = (float*)   alloc(sizeof(float)*(NN+256));
  float*    invv    = (float*)   alloc(sizeof(float)*(NN+256));
  float*    Kf      = (float*)   alloc(sizeof(float)*4*17*128);
  ushort_t* KfTf    = (ushort_t*)alloc(sizeof(ushort_t)*4*8*64*8);
  float*    Kfb     = (float*)   alloc(sizeof(float)*4*128);
  float*    bnpart  = (float*)   alloc(sizeof(float)*(size_t)MB2*256);
  float*    bnscale = (float*)   alloc(sizeof(float)*128);
  float*    bnshift = (float*)   alloc(sizeof(float)*128);
  float*    gpart   = (float*)   alloc(sizeof(float)*32*8*128);
  float*    g       = (float*)   alloc(sizeof(float)*32*128);
  float*    biasY   = (float*)   alloc(sizeof(float)*4*128);
  ushort_t* WembT   = (ushort_t*)alloc(sizeof(ushort_t)*128*64);
  ushort_t* P12T    = (ushort_t*)alloc(sizeof(ushort_t)*4*256*128);
  ushort_t* WcatFT  = (ushort_t*)alloc(sizeof(ushort_t)*(size_t)4*384*512);
  ushort_t* W0FT    = (ushort_t*)alloc(sizeof(ushort_t)*4*128*128);
  float* nembW = (float*)alloc(sizeof(float)*64*128);
  float* nembB = (float*)alloc(sizeof(float)*128);
  float* eembW = (float*)alloc(sizeof(float)*16*128);
  float* eembB = (float*)alloc(sizeof(float)*128);
  float* encW  = (float*)alloc(sizeof(float)*4*128*128);
  float* encB  = (float*)alloc(sizeof(float)*4*128);
  float* preW  = (float*)alloc(sizeof(float)*4*384*128);
  float* preB  = (float*)alloc(sizeof(float)*4*128);
  float* postW = (float*)alloc(sizeof(float)*(size_t)4*1664*128);
  float* postB = (float*)alloc(sizeof(float)*4*128);
  float* linW  = (float*)alloc(sizeof(float)*4*128*128);
  float* linB  = (float*)alloc(sizeof(float)*4*128);
  float* bnG   = (float*)alloc(sizeof(float)*4*128);
  float* bnB   = (float*)alloc(sizeof(float)*4*128);
  float* h1W   = (float*)alloc(sizeof(float)*128*64);
  float* h1B   = (float*)alloc(sizeof(float)*64);
  float* h2W   = (float*)alloc(sizeof(float)*64*12);
  float* h2B   = (float*)alloc(sizeof(float)*12);

  CvtArgs ca;
  ca.flag = dtflag;
  int ji = 0;
  auto job = [&](const void* s, float* d, int n){ ca.j[ji].s=s; ca.j[ji].d=d; ca.j[ji].n=n; ji++; };
  job(nembW_r, nembW, 64*128);
  job(nembB_r, nembB, 128);
  job(eembW_r, eembW, 16*128);
  job(eembB_r, eembB, 128);
  job(encW_r,  encW,  4*128*128);
  job(encB_r,  encB,  4*128);
  job(preW_r,  preW,  4*384*128);
  job(preB_r,  preB,  4*128);
  job(postW_r, postW, 4*1664*128);
  job(postB_r, postB, 4*128);
  job(linW_r,  linW,  4*128*128);
  job(linB_r,  linB,  4*128);
  job(bnG_r,   bnG,   4*128);
  job(bnB_r,   bnB,   4*128);
  job(h1W_r,   h1W,   128*64);
  job(h1B_r,   h1B,   64);
  job(h2W_r,   h2W,   64*12);
  job(h2B_r,   h2B,   12);

  TrArgs ta;
  int ti = 0;
  auto tj = [&](const float* s, ushort_t* d, int K, int N){ ta.j[ti].s=s; ta.j[ti].d=d; ta.j[ti].K=K; ta.j[ti].N=N; ti++; };
  tj(nembW, WembT, 64, 128);
  for(int l=0;l<4;l++){
    const float* pw = preW + (size_t)l*384*128;
    tj(pw,           P12T + (size_t)l*256*128,           128, 128);
    tj(pw + 128*128, P12T + (size_t)l*256*128 + 128*128, 128, 128);
  }

  FoldArgs fa;
  int fi = 0;
  for(int l=0;l<4;l++){
    const float* po = postW + (size_t)l*1664*128;
    const float* L  = linW + (size_t)l*128*128;
    for(int b=0;b<3;b++){
      fa.j[fi].s1 = po + (size_t)(128 + b*512)*128;
      fa.j[fi].s2 = L;
      fa.j[fi].d  = WcatFT + (size_t)l*384*512 + (size_t)b*128*512;
      fa.j[fi].Kd = 512;
      fi++;
    }
    fa.j[fi].s1 = po;
    fa.j[fi].s2 = L;
    fa.j[fi].d  = W0FT + (size_t)l*128*128;
    fa.j[fi].Kd = 128;
    fi++;
  }

  const int* esrc = eidx;
  const int* edst = eidx + NE;

  hipMemsetAsync(deg, 0, sizeof(int)*NN, stream);
  hipMemsetAsync(fill, 0, sizeof(int)*NN, stream);

  k_detect<<<1, 256, 0, stream>>>((const ushort_t*)x_raw, dtflag);
  k_cvt<<<dim3(128, NJOBS), 256, 0, stream>>>(ca);
  k_xbf<<<(NN*64+255)/256, 256, 0, stream>>>(x_raw, xbf, dtflag);
  k_tr<<<dim3(4, NTR), 256, 0, stream>>>(ta);
  k_fold<<<dim3(8, NFOLD), 256, 0, stream>>>(fa);
  k_foldb<<<4, 128, 0, stream>>>(postB, linW, linB, biasY);
  k_prep_K<<<68, 128, 0, stream>>>(eembW, eembB, encW, encB, preW, preB, Kf);
  k_prep_Kfrag<<<32, 64, 0, stream>>>(Kf, KfTf, Kfb);

  k_deg<<<(NE+255)/256, 256, 0, stream>>>(edst, deg);
  k_scan1<<<30, 1024, 0, stream>>>(deg, rp, bsum);
  k_scan2<<<1, 64, 0, stream>>>(bsum, boff, rp, 30);
  k_scan3<<<30, 1024, 0, stream>>>(rp, boff);
  k_scatter<<<(NE+255)/256, 256, 0, stream>>>(edst, rp, fill, eix_csr);
  k_srt<<<(NN+63)/64, 64, 0, stream>>>(rp, eix_csr);
  k_gather_ea<<<(NE+127)/128, 128, 0, stream>>>(eix_csr, esrc, ea_raw, ea_csr, src_csr, dtflag);

  // h = x @ Wemb + b  (bf16 out)
  k_mm<0,1><<<dim3(MB_GRID,1), 256, 0, stream>>>(xbf, WembT, h, nullptr, NN, 64, 128, nembB);

  for(int l=0; l<NLAYER; l++){
    // [Ah | Bh] = h @ [P1|P2]  (mixed fp32/bf16 out)
    k_mm<2,0><<<dim3(MB_GRID,2), 256, 0, stream>>>(h, P12T + (size_t)l*256*128, Ah, Bh,
                                                   NN, 128, 128, nullptr);
    k_agg<<<NN, 128, 0, stream>>>(rp, src_csr, ea_csr,
                                  KfTf + (size_t)l*8*64*8, Kfb + l*128,
                                  Ah, Bh, aggb, ampv, invv);
    // y = agg@WcatF (amp-combined) + h@W0f + biasY  (bf16 out + BN partials)
    k_post<<<MB2, 256, 0, stream>>>(aggb, h, WcatFT + (size_t)l*384*512,
                                    W0FT + (size_t)l*128*128, biasY + l*128,
                                    ampv, invv, y, bnpart);
    k_bn_fin<<<1, 128, 0, stream>>>(bnpart, MB2, bnG + l*128, bnB + l*128,
                                    bnscale, bnshift);
    k_bn_relu<<<(NN*128+255)/256, 256, 0, stream>>>(y, bnscale, bnshift, h);
  }

  k_pool1<<<dim3(NGR,8), 128, 0, stream>>>(h, batch, gpart);
  k_pool2<<<NGR, 128, 0, stream>>>(gpart, g);
  k_head<<<NGR, 64, 0, stream>>>(g, h1W, h1B, h2W, h2B, d_out, dtflag);
}